// Round 5
// baseline (21.109 us; speedup 1.0000x reference)
//
#include <hip/hip_runtime.h>
#include <math.h>

#define NW     21
#define EMB    256
#define TOKB   16          // tokens per block
#define LN_EPS 1e-5f
// XOR-swizzle on LDS word index: spreads 128-word-strided lanes across banks,
// preserves 4-word (b128) contiguity.
#define SWZ(w) ((w) ^ ((((w) >> 7) & 7) << 2))

struct cpx { float re, im; };
__device__ inline cpx cmul(cpx a, cpx b){ return cpx{a.re*b.re - a.im*b.im, a.re*b.im + a.im*b.re}; }
__device__ inline cpx cadd(cpx a, cpx b){ return cpx{a.re+b.re, a.im+b.im}; }
__device__ inline cpx cscale(cpx a, float s){ return cpx{a.re*s, a.im*s}; }
__device__ inline cpx cexp_i(float t){ float s,c; sincosf(t,&s,&c); return cpx{c,s}; }

// suffix basis chain for one e -> 8 floats into swizzled e-major sSt
__device__ inline void suffix_store(int e, const cpx (*sA)[2], const cpx (*sU)[2][2],
                                    float* sSt)
{
    cpx M[2][2];
    #pragma unroll
    for (int j = 0; j < 2; ++j) {
        cpx w0 = (j == 0) ? cpx{1.f,0.f} : cpx{0.f,0.f};
        cpx w1 = (j == 0) ? cpx{0.f,0.f} : cpx{1.f,0.f};
        #pragma unroll
        for (int i = 13; i <= 19; ++i) {
            int ni = (e >> (20-i)) & 1;
            cpx t0 = cadd(cmul(w0, sA[i][0]), cmul(w1, sA[i][1]));
            cpx t1 = cadd(cmul(w0, sA[i][1]), cmul(w1, sA[i][0]));
            w0 = cmul(sU[i][ni][0], t0);
            w1 = cmul(sU[i][ni][1], t1);
        }
        M[0][j] = w0; M[1][j] = w1;
    }
    const int n20 = e & 1;
    float o8[8];
    #pragma unroll
    for (int s = 0; s < 2; ++s) {
        #pragma unroll
        for (int j = 0; j < 2; ++j) {
            cpx d = cadd(cmul(M[0][j], sA[20][s]), cmul(M[1][j], sA[20][1^s]));
            cpx S = cmul(sU[20][n20][s], d);
            o8[s*4 + j*2 + 0] = S.re;
            o8[s*4 + j*2 + 1] = S.im;
        }
    }
    const int w = e * 8;
    *(float4*)&sSt[SWZ(w)]     = *(float4*)&o8[0];
    *(float4*)&sSt[SWZ(w + 4)] = *(float4*)&o8[4];
}

// One kernel; 1024 blocks x 256 thr (4 waves), 16 tokens/block, 4 blocks/CU.
//  phase 0: tid<21 gate constants -> LDS ; barrier
//  phase 1: wave 0 lanes 0-31: all 32 prefix chains (16 tok x 2 s) -> sP4
//           waves 1-3: 256 suffix chains (wave 1 does 2 each) -> sSt ; barrier
//  phase 2: lane l -> token (l>>4) of its wave, e-range (l&15)*16..+15.
//           16 e's per lane, LN reduce = 4 shuffle levels in 16-lane group,
//           4 tokens per wave reduced simultaneously.
__global__ __launch_bounds__(256, 4) void qembed_one(
    const int*   __restrict__ x,
    const float* __restrict__ rp1,
    const float* __restrict__ rp2,
    const float* __restrict__ gamma,
    const float* __restrict__ beta,
    float*       __restrict__ out,
    int ntok)
{
    __shared__ cpx    sA[NW][2];
    __shared__ cpx    sU[NW][2][2];
    __shared__ float  sSt[EMB*8];        // e-major suffix table, XOR-swizzled
    __shared__ float4 sP4[TOKB][2];

    const int tid      = threadIdx.x;
    const int lane     = tid & 63;
    const int wv       = tid >> 6;
    const int g        = lane & 15;      // e-chunk
    const int tslot    = lane >> 4;      // token slot within wave
    const int E0       = g * 16;
    const int blockTok = blockIdx.x * TOKB;
    const int tok      = blockTok + wv*4 + tslot;

    // hoisted global loads (latency hides under gate build + phase 1)
    float4 gg[4], bb[4];
    #pragma unroll
    for (int q = 0; q < 4; ++q) {
        gg[q] = *(const float4*)(gamma + E0 + q*4);
        bb[q] = *(const float4*)(beta  + E0 + q*4);
    }
    int pv = 0;
    if (tid < 32) {
        int idx = blockTok + (tid >> 1);
        if (idx >= ntok) idx = ntok - 1;
        pv = x[idx];
    }

    if (tid < NW) {
        float p = rp1[tid*3+0], th = rp1[tid*3+1], om = rp1[tid*3+2];
        float st, ct; sincosf(0.5f*th, &st, &ct);
        cpx em = cexp_i(-0.5f*(p+om));
        cpx ed = cexp_i(-0.5f*(p-om));
        sA[tid][0] = cscale(em, ct);
        sA[tid][1] = cscale(ed, st);
        p = rp2[tid*3+0]; th = rp2[tid*3+1]; om = rp2[tid*3+2];
        sincosf(0.5f*th, &st, &ct);
        em = cexp_i(-0.5f*(p+om));
        ed = cexp_i(-0.5f*(p-om));
        sU[tid][0][0] = cscale(em, ct);
        sU[tid][1][1] = cpx{ em.re*ct, -em.im*ct};
        sU[tid][1][0] = cscale(ed, st);
        sU[tid][0][1] = cpx{-ed.re*st,  ed.im*st};
    }
    __syncthreads();

    if (tid < 64) {
        if (tid < 32) {
            // all 32 prefix chains: lane -> (token k, closure-bit s)
            const int k = tid >> 1, s = tid & 1;
            const int v = pv;
            int n0 = (v >> 12) & 1;
            cpx w0 = cmul(sU[0][n0][0], sA[0][s]);
            cpx w1 = cmul(sU[0][n0][1], sA[0][1^s]);
            #pragma unroll
            for (int i = 1; i <= 12; ++i) {
                int ni = (v >> (12-i)) & 1;
                int sb = (i == 1) ? s : 0;
                cpx t0 = cadd(cmul(w0, sA[i][sb]),   cmul(w1, sA[i][1^sb]));
                cpx t1 = cadd(cmul(w0, sA[i][1^sb]), cmul(w1, sA[i][sb]));
                w0 = cmul(sU[i][ni][0], t0);
                w1 = cmul(sU[i][ni][1], t1);
            }
            sP4[k][s] = make_float4(w0.re, w0.im, w1.re, w1.im);
        }
    } else {
        suffix_store(tid - 64, sA, sU, sSt);              // e in [0,192)
        if (tid < 128) suffix_store(tid + 128, sA, sU, sSt); // e in [192,256)
    }
    __syncthreads();

    // ---- phase 2 ----
    const float4 p0 = sP4[wv*4 + tslot][0];
    const float4 p1 = sP4[wv*4 + tslot][1];

    float mags[16];
    float lsum = 0.f, lsq = 0.f;
    #pragma unroll
    for (int k = 0; k < 16; ++k) {
        const int w = (E0 + k) * 8;
        const float4 s01 = *(const float4*)&sSt[SWZ(w)];
        const float4 s23 = *(const float4*)&sSt[SWZ(w + 4)];
        float re = p0.x*s01.x - p0.y*s01.y
                 + p0.z*s01.z - p0.w*s01.w
                 + p1.x*s23.x - p1.y*s23.y
                 + p1.z*s23.z - p1.w*s23.w;
        float im = p0.x*s01.y + p0.y*s01.x
                 + p0.z*s01.w + p0.w*s01.z
                 + p1.x*s23.y + p1.y*s23.x
                 + p1.z*s23.w + p1.w*s23.z;
        const float m = __builtin_amdgcn_sqrtf(re*re + im*im);
        mags[k] = m; lsum += m; lsq += m*m;
    }

    // LN reduce within the 16-lane group (4 tokens per wave in parallel)
    #pragma unroll
    for (int off = 1; off <= 8; off <<= 1) {
        lsum += __shfl_xor(lsum, off);
        lsq  += __shfl_xor(lsq,  off);
    }
    const float mu = lsum * (1.0f/EMB);
    float var = lsq * (1.0f/EMB) - mu*mu;
    if (var < 0.f) var = 0.f;
    const float rs = __builtin_amdgcn_rsqf(var + LN_EPS);

    if (tok < ntok) {
        float* op = out + (size_t)tok*EMB + E0;
        #pragma unroll
        for (int q = 0; q < 4; ++q) {
            float4 o;
            o.x = (mags[q*4+0]-mu)*rs*gg[q].x + bb[q].x;
            o.y = (mags[q*4+1]-mu)*rs*gg[q].y + bb[q].y;
            o.z = (mags[q*4+2]-mu)*rs*gg[q].z + bb[q].z;
            o.w = (mags[q*4+3]-mu)*rs*gg[q].w + bb[q].w;
            *(float4*)(op + q*4) = o;
        }
    }
}

extern "C" void kernel_launch(void* const* d_in, const int* in_sizes, int n_in,
                              void* d_out, int out_size, void* d_ws, size_t ws_size,
                              hipStream_t stream) {
    const int*   x     = (const int*)  d_in[0];
    const float* rp1   = (const float*)d_in[1];
    const float* rp2   = (const float*)d_in[2];
    const float* gamma = (const float*)d_in[3];
    const float* beta  = (const float*)d_in[4];
    float* out = (float*)d_out;
    const int ntok = in_sizes[0];                    // B*S = 16384
    const int nblocks = (ntok + TOKB - 1) / TOKB;    // 1024
    qembed_one<<<nblocks, 256, 0, stream>>>(x, rp1, rp2, gamma, beta, out, ntok);
}

// Round 6
// 15.532 us; speedup vs baseline: 1.3591x; 1.3591x over previous
//
#include <hip/hip_runtime.h>
#include <math.h>

#define NW     21
#define EMB    256
#define TOKB   64          // tokens per block
#define LN_EPS 1e-5f

struct cpx { float re, im; };
__device__ inline cpx cmul(cpx a, cpx b){ return cpx{a.re*b.re - a.im*b.im, a.re*b.im + a.im*b.re}; }
__device__ inline cpx cadd(cpx a, cpx b){ return cpx{a.re+b.re, a.im+b.im}; }
__device__ inline cpx cscale(cpx a, float s){ return cpx{a.re*s, a.im*s}; }
__device__ inline cpx cexp_i(float t){ float s,c; sincosf(t,&s,&c); return cpx{c,s}; }

// One G-step: (m0,m1) <- (G0*m0 + G1*m1, G2*m0 + G3*m1)
// a = (G0.re,G0.im,G1.re,G1.im), b = (G2.re,G2.im,G3.re,G3.im)  [16 FMA]
__device__ inline void gstep(const float4 a, const float4 b,
                             float& r0, float& i0, float& r1, float& i1)
{
    float nr0 = a.x*r0 - a.y*i0 + a.z*r1 - a.w*i1;
    float ni0 = a.x*i0 + a.y*r0 + a.z*i1 + a.w*r1;
    float nr1 = b.x*r0 - b.y*i0 + b.z*r1 - b.w*i1;
    float ni1 = b.x*i0 + b.y*r0 + b.z*i1 + b.w*r1;
    r0 = nr0; i0 = ni0; r1 = nr1; i1 = ni1;
}

// 256 blocks x 512 threads (8 waves), 64 tokens/block, 1 block/CU.
//  phase 0 : tid<21 gate constants (sA layer-1 col0, sU layer-2)
//  phase 0':  step-matrix tables: sG (wires 2..19), sInit (wires 0+1), sK (wire 20)
//  phase 1 : tid<256  suffix chain e=tid  (wire-13 lookup + 6 G-steps + K-epilogue)
//            tid 256..383: 128 prefix chains (64 tok x 2 s) = Init + 11 G-steps
//  phase 2 : R4-proven: wave handles 8 tokens, lane owns 4 e's; batched butterfly.
__global__ __launch_bounds__(512) void qembed_one(
    const int*   __restrict__ x,
    const float* __restrict__ rp1,
    const float* __restrict__ rp2,
    const float* __restrict__ gamma,
    const float* __restrict__ beta,
    float*       __restrict__ out,
    int ntok)
{
    __shared__ cpx    sA[NW][2];
    __shared__ cpx    sU[NW][2][2];
    __shared__ float  sG[18][2][8];      // wires 2..19: [w-2][n][4 cpx]
    __shared__ float4 sInit[2][2][2];    // [n0][n1][s] -> (w0,w1)
    __shared__ float  sK[2][2][4];       // [s][n20] -> (K0,K1)
    __shared__ float  sSt[8][EMB];       // suffix components, component-major
    __shared__ float4 sP4[TOKB][2];      // prefix vectors per (token, s)

    const int tid      = threadIdx.x;
    const int lane     = tid & 63;
    const int wv       = tid >> 6;       // 0..7
    const int e0       = lane * 4;
    const int blockTok = blockIdx.x * TOKB;

    // hoisted global loads
    const float4 g4 = *(const float4*)(gamma + e0);
    const float4 b4 = *(const float4*)(beta  + e0);
    int pv = 0;
    if (tid >= 256 && tid < 384) {
        int idx = blockTok + ((tid - 256) >> 1);
        if (idx >= ntok) idx = ntok - 1;
        pv = x[idx];
    }

    // ---- phase 0: gate constants ----
    if (tid < NW) {
        float p = rp1[tid*3+0], th = rp1[tid*3+1], om = rp1[tid*3+2];
        float st, ct; sincosf(0.5f*th, &st, &ct);
        cpx em = cexp_i(-0.5f*(p+om));
        cpx ed = cexp_i(-0.5f*(p-om));
        sA[tid][0] = cscale(em, ct);
        sA[tid][1] = cscale(ed, st);
        p = rp2[tid*3+0]; th = rp2[tid*3+1]; om = rp2[tid*3+2];
        sincosf(0.5f*th, &st, &ct);
        em = cexp_i(-0.5f*(p+om));
        ed = cexp_i(-0.5f*(p-om));
        sU[tid][0][0] = cscale(em, ct);
        sU[tid][1][1] = cpx{ em.re*ct, -em.im*ct};
        sU[tid][1][0] = cscale(ed, st);
        sU[tid][0][1] = cpx{-ed.re*st,  ed.im*st};
    }
    __syncthreads();

    // ---- phase 0': step-matrix tables ----
    if (tid < 144) {
        const int w = 2 + tid/8, n = (tid >> 2) & 1, c = tid & 3;
        const int row = c >> 1;                       // c:0,1->row0 ; 2,3->row1
        const int ai  = (c == 1 || c == 2) ? 1 : 0;   // A index per entry
        cpx g = cmul(sU[w][n][row], sA[w][ai]);
        sG[w-2][n][c*2]   = g.re;
        sG[w-2][n][c*2+1] = g.im;
    } else if (tid < 152) {
        const int idx = tid - 144;
        const int n0 = (idx >> 2) & 1, n1 = (idx >> 1) & 1, s = idx & 1;
        cpx w0 = cmul(sU[0][n0][0], sA[0][s]);
        cpx w1 = cmul(sU[0][n0][1], sA[0][1^s]);
        cpx t0 = cadd(cmul(w0, sA[1][s]),   cmul(w1, sA[1][1^s]));
        cpx t1 = cadd(cmul(w0, sA[1][1^s]), cmul(w1, sA[1][s]));
        w0 = cmul(sU[1][n1][0], t0);
        w1 = cmul(sU[1][n1][1], t1);
        sInit[n0][n1][s] = make_float4(w0.re, w0.im, w1.re, w1.im);
    } else if (tid < 160) {
        const int idx = tid - 152;
        const int s = (idx >> 2) & 1, n = (idx >> 1) & 1, c = idx & 1;
        cpx g = cmul(sU[20][n][s], sA[20][c ? (1^s) : s]);
        sK[s][n][c*2]   = g.re;
        sK[s][n][c*2+1] = g.im;
    }
    __syncthreads();

    // ---- phase 1 ----
    if (tid < 256) {
        // suffix chain for e = tid: wire-13 lookup, 6 G-steps, K-epilogue
        const int e = tid;
        const int n13 = (e >> 7) & 1;
        float4 ga = *(const float4*)&sG[11][n13][0];   // entries 0,1
        float4 gb = *(const float4*)&sG[11][n13][4];   // entries 2,3
        // column j=0 = (G0,G2); column j=1 = (G1,G3)
        float r00 = ga.x, i00 = ga.y, r10 = gb.x, i10 = gb.y;   // M[0][0],M[1][0]
        float r01 = ga.z, i01 = ga.w, r11 = gb.z, i11 = gb.w;   // M[0][1],M[1][1]
        #pragma unroll
        for (int i = 14; i <= 19; ++i) {
            const int ni = (e >> (20-i)) & 1;
            float4 a = *(const float4*)&sG[i-2][ni][0];
            float4 b = *(const float4*)&sG[i-2][ni][4];
            gstep(a, b, r00, i00, r10, i10);
            gstep(a, b, r01, i01, r11, i11);
        }
        const int n20 = e & 1;
        float o8[8];
        #pragma unroll
        for (int s = 0; s < 2; ++s) {
            const float4 k4 = *(const float4*)&sK[s][n20][0];  // (K0,K1)
            // S(s,j) = K0*M[0][j] + K1*M[1][j]
            o8[s*4+0] = k4.x*r00 - k4.y*i00 + k4.z*r10 - k4.w*i10;
            o8[s*4+1] = k4.x*i00 + k4.y*r00 + k4.z*i10 + k4.w*r10;
            o8[s*4+2] = k4.x*r01 - k4.y*i01 + k4.z*r11 - k4.w*i11;
            o8[s*4+3] = k4.x*i01 + k4.y*r01 + k4.z*i11 + k4.w*r11;
        }
        #pragma unroll
        for (int c = 0; c < 8; ++c) sSt[c][e] = o8[c];
    } else if (tid < 384) {
        // prefix chain: idx -> (token k, closure-bit s)
        const int idx = tid - 256;
        const int k = idx >> 1, s = idx & 1;
        const int v = pv;
        const int n0 = (v >> 12) & 1, n1 = (v >> 11) & 1;
        const float4 in4 = sInit[n0][n1][s];
        float r0 = in4.x, i0 = in4.y, r1 = in4.z, i1 = in4.w;
        #pragma unroll
        for (int i = 2; i <= 12; ++i) {
            const int ni = (v >> (12-i)) & 1;
            float4 a = *(const float4*)&sG[i-2][ni][0];
            float4 b = *(const float4*)&sG[i-2][ni][4];
            gstep(a, b, r0, i0, r1, i1);
        }
        sP4[k][s] = make_float4(r0, i0, r1, i1);
    }
    __syncthreads();

    // ---- phase 2 (R4-proven) ----
    float sr[8][4];
    #pragma unroll
    for (int c = 0; c < 8; ++c) {
        float4 t = *(const float4*)&sSt[c][e0];
        sr[c][0] = t.x; sr[c][1] = t.y; sr[c][2] = t.z; sr[c][3] = t.w;
    }

    float mags[8][4];
    float ls[8], lq[8];
    #pragma unroll
    for (int t = 0; t < 8; ++t) {
        const int k = wv*8 + t;
        const float4 p0 = sP4[k][0];
        const float4 p1 = sP4[k][1];
        float s_ = 0.f, q_ = 0.f;
        #pragma unroll
        for (int kk = 0; kk < 4; ++kk) {
            float re = p0.x*sr[0][kk] - p0.y*sr[1][kk]
                     + p0.z*sr[2][kk] - p0.w*sr[3][kk]
                     + p1.x*sr[4][kk] - p1.y*sr[5][kk]
                     + p1.z*sr[6][kk] - p1.w*sr[7][kk];
            float im = p0.x*sr[1][kk] + p0.y*sr[0][kk]
                     + p0.z*sr[3][kk] + p0.w*sr[2][kk]
                     + p1.x*sr[5][kk] + p1.y*sr[4][kk]
                     + p1.z*sr[7][kk] + p1.w*sr[6][kk];
            const float m = __builtin_amdgcn_sqrtf(re*re + im*im);
            mags[t][kk] = m; s_ += m; q_ += m*m;
        }
        ls[t] = s_; lq[t] = q_;
    }

    // batched butterfly: 16 independent chains per level
    #pragma unroll
    for (int off = 32; off; off >>= 1) {
        #pragma unroll
        for (int t = 0; t < 8; ++t) {
            ls[t] += __shfl_xor(ls[t], off);
            lq[t] += __shfl_xor(lq[t], off);
        }
    }

    #pragma unroll
    for (int t = 0; t < 8; ++t) {
        const int tok = blockTok + wv*8 + t;
        const float mu = ls[t] * (1.0f/EMB);
        float var = lq[t] * (1.0f/EMB) - mu*mu;
        if (var < 0.f) var = 0.f;
        const float rs = __builtin_amdgcn_rsqf(var + LN_EPS);
        if (tok < ntok) {
            float4 o;
            o.x = (mags[t][0]-mu)*rs*g4.x + b4.x;
            o.y = (mags[t][1]-mu)*rs*g4.y + b4.y;
            o.z = (mags[t][2]-mu)*rs*g4.z + b4.z;
            o.w = (mags[t][3]-mu)*rs*g4.w + b4.w;
            *(float4*)(out + (size_t)tok*EMB + e0) = o;
        }
    }
}

extern "C" void kernel_launch(void* const* d_in, const int* in_sizes, int n_in,
                              void* d_out, int out_size, void* d_ws, size_t ws_size,
                              hipStream_t stream) {
    const int*   x     = (const int*)  d_in[0];
    const float* rp1   = (const float*)d_in[1];
    const float* rp2   = (const float*)d_in[2];
    const float* gamma = (const float*)d_in[3];
    const float* beta  = (const float*)d_in[4];
    float* out = (float*)d_out;
    const int ntok = in_sizes[0];                    // B*S = 16384
    const int nblocks = (ntok + TOKB - 1) / TOKB;    // 256
    qembed_one<<<nblocks, 512, 0, stream>>>(x, rp1, rp2, gamma, beta, out, ntok);
}

// Round 7
// 14.589 us; speedup vs baseline: 1.4469x; 1.0646x over previous
//
#include <hip/hip_runtime.h>
#include <math.h>

#define NW     21
#define EMB    256
#define TOKB   64          // tokens per block
#define LN_EPS 1e-5f

struct cpx { float re, im; };
__device__ inline cpx cmul(cpx a, cpx b){ return cpx{a.re*b.re - a.im*b.im, a.re*b.im + a.im*b.re}; }
__device__ inline cpx cadd(cpx a, cpx b){ return cpx{a.re+b.re, a.im+b.im}; }

// One G-step: (m0,m1) <- (G0*m0 + G1*m1, G2*m0 + G3*m1)
__device__ inline void gstep(const float4 a, const float4 b,
                             float& r0, float& i0, float& r1, float& i1)
{
    float nr0 = a.x*r0 - a.y*i0 + a.z*r1 - a.w*i1;
    float ni0 = a.x*i0 + a.y*r0 + a.z*i1 + a.w*r1;
    float nr1 = b.x*r0 - b.y*i0 + b.z*r1 - b.w*i1;
    float ni1 = b.x*i0 + b.y*r0 + b.z*i1 + b.w*r1;
    r0 = nr0; i0 = ni0; r1 = nr1; i1 = ni1;
}

// 256 blocks x 1024 threads (16 waves), 64 tokens/block, 16 waves/CU (4/SIMD).
//  trig    : 126 threads, one sincosf each -> sTrig
//  assemble: tid<21 builds sA/sU from sTrig (cheap)
//  tables  : sG (wires 2..19), sInit (wires 0+1), sK (wire 20)
//  phase 1 : tid<256 suffix chain e=tid; tid 256..383 prefix chains (64 tok x 2 s)
//  phase 2 : wave wv handles tokens wv*4..wv*4+3; lane owns e = 4*lane..4*lane+3;
//            batched 6-level butterfly (8 chains); float4 stores.
__global__ __launch_bounds__(1024, 4) void qembed_one(
    const int*   __restrict__ x,
    const float* __restrict__ rp1,
    const float* __restrict__ rp2,
    const float* __restrict__ gamma,
    const float* __restrict__ beta,
    float*       __restrict__ out,
    int ntok)
{
    __shared__ float2 sTrig[2][NW][3];   // [layer][wire][kind] = (cos, sin)
    __shared__ cpx    sA[NW][2];
    __shared__ cpx    sU[NW][2][2];
    __shared__ float  sG[18][2][8];      // wires 2..19: [w-2][n][4 cpx]
    __shared__ float4 sInit[2][2][2];    // [n0][n1][s] -> (w0,w1)
    __shared__ float  sK[2][2][4];       // [s][n20] -> (K0,K1)
    __shared__ float  sSt[8][EMB];       // suffix components, component-major
    __shared__ float4 sP4[TOKB][2];      // prefix vectors per (token, s)

    const int tid      = threadIdx.x;
    const int lane     = tid & 63;
    const int wv       = tid >> 6;       // 0..15
    const int e0       = lane * 4;
    const int blockTok = blockIdx.x * TOKB;

    // hoisted global loads
    const float4 g4 = *(const float4*)(gamma + e0);
    const float4 b4 = *(const float4*)(beta  + e0);
    int pv = 0;
    if (tid >= 256 && tid < 384) {
        int idx = blockTok + ((tid - 256) >> 1);
        if (idx >= ntok) idx = ntok - 1;
        pv = x[idx];
    }

    // ---- trig: one sincosf per thread ----
    if (tid < 126) {
        const int layer = tid / 63, r = tid % 63, w = r / 3, kind = r % 3;
        const float* rp = layer ? rp2 : rp1;
        const float p = rp[w*3+0], th = rp[w*3+1], om = rp[w*3+2];
        const float arg = (kind == 0) ? 0.5f*th
                        : (kind == 1) ? -0.5f*(p+om)
                                      : -0.5f*(p-om);
        float s, c; sincosf(arg, &s, &c);
        sTrig[layer][w][kind] = make_float2(c, s);
    }
    __syncthreads();

    // ---- assemble gate constants ----
    if (tid < NW) {
        const int w = tid;
        float2 t0 = sTrig[0][w][0], em1 = sTrig[0][w][1], ed1 = sTrig[0][w][2];
        const float ct = t0.x, st = t0.y;
        sA[w][0] = cpx{em1.x*ct, em1.y*ct};
        sA[w][1] = cpx{ed1.x*st, ed1.y*st};
        float2 t1 = sTrig[1][w][0], em2 = sTrig[1][w][1], ed2 = sTrig[1][w][2];
        const float ct2 = t1.x, st2 = t1.y;
        sU[w][0][0] = cpx{ em2.x*ct2,  em2.y*ct2};
        sU[w][1][1] = cpx{ em2.x*ct2, -em2.y*ct2};
        sU[w][1][0] = cpx{ ed2.x*st2,  ed2.y*st2};
        sU[w][0][1] = cpx{-ed2.x*st2,  ed2.y*st2};
    }
    __syncthreads();

    // ---- step-matrix tables ----
    if (tid < 144) {
        const int w = 2 + tid/8, n = (tid >> 2) & 1, c = tid & 3;
        const int row = c >> 1;
        const int ai  = (c == 1 || c == 2) ? 1 : 0;
        cpx g = cmul(sU[w][n][row], sA[w][ai]);
        sG[w-2][n][c*2]   = g.re;
        sG[w-2][n][c*2+1] = g.im;
    } else if (tid < 152) {
        const int idx = tid - 144;
        const int n0 = (idx >> 2) & 1, n1 = (idx >> 1) & 1, s = idx & 1;
        cpx w0 = cmul(sU[0][n0][0], sA[0][s]);
        cpx w1 = cmul(sU[0][n0][1], sA[0][1^s]);
        cpx t0 = cadd(cmul(w0, sA[1][s]),   cmul(w1, sA[1][1^s]));
        cpx t1 = cadd(cmul(w0, sA[1][1^s]), cmul(w1, sA[1][s]));
        w0 = cmul(sU[1][n1][0], t0);
        w1 = cmul(sU[1][n1][1], t1);
        sInit[n0][n1][s] = make_float4(w0.re, w0.im, w1.re, w1.im);
    } else if (tid < 160) {
        const int idx = tid - 152;
        const int s = (idx >> 2) & 1, n = (idx >> 1) & 1, c = idx & 1;
        cpx g = cmul(sU[20][n][s], sA[20][c ? (1^s) : s]);
        sK[s][n][c*2]   = g.re;
        sK[s][n][c*2+1] = g.im;
    }
    __syncthreads();

    // ---- phase 1 ----
    if (tid < 256) {
        const int e = tid;
        const int n13 = (e >> 7) & 1;
        float4 ga = *(const float4*)&sG[11][n13][0];
        float4 gb = *(const float4*)&sG[11][n13][4];
        float r00 = ga.x, i00 = ga.y, r10 = gb.x, i10 = gb.y;
        float r01 = ga.z, i01 = ga.w, r11 = gb.z, i11 = gb.w;
        #pragma unroll
        for (int i = 14; i <= 19; ++i) {
            const int ni = (e >> (20-i)) & 1;
            float4 a = *(const float4*)&sG[i-2][ni][0];
            float4 b = *(const float4*)&sG[i-2][ni][4];
            gstep(a, b, r00, i00, r10, i10);
            gstep(a, b, r01, i01, r11, i11);
        }
        const int n20 = e & 1;
        float o8[8];
        #pragma unroll
        for (int s = 0; s < 2; ++s) {
            const float4 k4 = *(const float4*)&sK[s][n20][0];
            o8[s*4+0] = k4.x*r00 - k4.y*i00 + k4.z*r10 - k4.w*i10;
            o8[s*4+1] = k4.x*i00 + k4.y*r00 + k4.z*i10 + k4.w*r10;
            o8[s*4+2] = k4.x*r01 - k4.y*i01 + k4.z*r11 - k4.w*i11;
            o8[s*4+3] = k4.x*i01 + k4.y*r01 + k4.z*i11 + k4.w*r11;
        }
        #pragma unroll
        for (int c = 0; c < 8; ++c) sSt[c][e] = o8[c];
    } else if (tid < 384) {
        const int idx = tid - 256;
        const int k = idx >> 1, s = idx & 1;
        const int v = pv;
        const int n0 = (v >> 12) & 1, n1 = (v >> 11) & 1;
        const float4 in4 = sInit[n0][n1][s];
        float r0 = in4.x, i0 = in4.y, r1 = in4.z, i1 = in4.w;
        #pragma unroll
        for (int i = 2; i <= 12; ++i) {
            const int ni = (v >> (12-i)) & 1;
            float4 a = *(const float4*)&sG[i-2][ni][0];
            float4 b = *(const float4*)&sG[i-2][ni][4];
            gstep(a, b, r0, i0, r1, i1);
        }
        sP4[k][s] = make_float4(r0, i0, r1, i1);
    }
    __syncthreads();

    // ---- phase 2: 4 tokens per wave ----
    float sr[8][4];
    #pragma unroll
    for (int c = 0; c < 8; ++c) {
        float4 t = *(const float4*)&sSt[c][e0];
        sr[c][0] = t.x; sr[c][1] = t.y; sr[c][2] = t.z; sr[c][3] = t.w;
    }

    float mags[4][4];
    float ls[4], lq[4];
    #pragma unroll
    for (int t = 0; t < 4; ++t) {
        const int k = wv*4 + t;
        const float4 p0 = sP4[k][0];
        const float4 p1 = sP4[k][1];
        float s_ = 0.f, q_ = 0.f;
        #pragma unroll
        for (int kk = 0; kk < 4; ++kk) {
            float re = p0.x*sr[0][kk] - p0.y*sr[1][kk]
                     + p0.z*sr[2][kk] - p0.w*sr[3][kk]
                     + p1.x*sr[4][kk] - p1.y*sr[5][kk]
                     + p1.z*sr[6][kk] - p1.w*sr[7][kk];
            float im = p0.x*sr[1][kk] + p0.y*sr[0][kk]
                     + p0.z*sr[3][kk] + p0.w*sr[2][kk]
                     + p1.x*sr[5][kk] + p1.y*sr[4][kk]
                     + p1.z*sr[7][kk] + p1.w*sr[6][kk];
            const float m = __builtin_amdgcn_sqrtf(re*re + im*im);
            mags[t][kk] = m; s_ += m; q_ += m*m;
        }
        ls[t] = s_; lq[t] = q_;
    }

    #pragma unroll
    for (int off = 32; off; off >>= 1) {
        #pragma unroll
        for (int t = 0; t < 4; ++t) {
            ls[t] += __shfl_xor(ls[t], off);
            lq[t] += __shfl_xor(lq[t], off);
        }
    }

    #pragma unroll
    for (int t = 0; t < 4; ++t) {
        const int tok = blockTok + wv*4 + t;
        const float mu = ls[t] * (1.0f/EMB);
        float var = lq[t] * (1.0f/EMB) - mu*mu;
        if (var < 0.f) var = 0.f;
        const float rs = __builtin_amdgcn_rsqf(var + LN_EPS);
        if (tok < ntok) {
            float4 o;
            o.x = (mags[t][0]-mu)*rs*g4.x + b4.x;
            o.y = (mags[t][1]-mu)*rs*g4.y + b4.y;
            o.z = (mags[t][2]-mu)*rs*g4.z + b4.z;
            o.w = (mags[t][3]-mu)*rs*g4.w + b4.w;
            *(float4*)(out + (size_t)tok*EMB + e0) = o;
        }
    }
}

extern "C" void kernel_launch(void* const* d_in, const int* in_sizes, int n_in,
                              void* d_out, int out_size, void* d_ws, size_t ws_size,
                              hipStream_t stream) {
    const int*   x     = (const int*)  d_in[0];
    const float* rp1   = (const float*)d_in[1];
    const float* rp2   = (const float*)d_in[2];
    const float* gamma = (const float*)d_in[3];
    const float* beta  = (const float*)d_in[4];
    float* out = (float*)d_out;
    const int ntok = in_sizes[0];                    // B*S = 16384
    const int nblocks = (ntok + TOKB - 1) / TOKB;    // 256
    qembed_one<<<nblocks, 1024, 0, stream>>>(x, rp1, rp2, gamma, beta, out, ntok);
}